// Round 13
// baseline (198.418 us; speedup 1.0000x reference)
//
#include <hip/hip_runtime.h>
#include <stdint.h>

// y[b,s,m] = sum_n x[b,s,n] * W[m,n] + bias[m], W from TT cores (bf16, built once).
// Pipeline: prep (build_w + convert_x fused) -> 8-phase 256^2 GEMM.
// GEMM: A = bf16 X, B = bf16 W, both via global_load_lds, both staged TWO tiles
// ahead (A: triple-buffered LDS, 96 KB; B: double-buffered + reg pipeline).
// Single counted vmcnt(4) per tile at q1 drains A(t+1)+B(t+1) (issued 6-8
// phases earlier -> HBM latency covered); q3 has NO wait in steady state.
// All cross-wave LDS reads: drain -> barrier -> read (round-11 proof pattern).
// Frag ds_reads in post-MFMA tail of previous phase; ksub-outer MFMA order.
// MFMA operands swapped (W-frag first) -> D transposed -> f32x4 coalesced stores.

typedef __attribute__((ext_vector_type(8))) __bf16 bf16x8;
typedef __attribute__((ext_vector_type(4))) float f32x4;
typedef __attribute__((ext_vector_type(4))) unsigned short us4;
typedef __attribute__((ext_vector_type(8))) unsigned short us8;

#define M_TOT 16384
#define N_TOT 2048
#define K_TOT 2048

__device__ __forceinline__ unsigned short f2bf(float f) {
  union { float f; unsigned u; } v; v.f = f;
  unsigned u = v.u;
  u += 0x7FFFu + ((u >> 16) & 1u);   // RNE
  return (unsigned short)(u >> 16);
}

__device__ __forceinline__ void gld_lds16(const void* g, void* l) {
  __builtin_amdgcn_global_load_lds(
      (const __attribute__((address_space(1))) unsigned int*)g,
      (__attribute__((address_space(3))) unsigned int*)l, 16, 0, 0);
}

#define BARRIER() __builtin_amdgcn_s_barrier()
#define WAIT_LGKM0() asm volatile("s_waitcnt lgkmcnt(0)" ::: "memory")
#define WAIT_VM(N) asm volatile("s_waitcnt vmcnt(" #N ")" ::: "memory")

// ---------------------------------------------------------------------------
// Kernel 1: fused prep. Blocks [0,nconv): X fp32->bf16 (1 us8/thread);
// blocks [nconv, nconv+16384): build W bf16 from TT cores.
// ---------------------------------------------------------------------------
__global__ void prep_kernel(const float* __restrict__ X,
                            unsigned short* __restrict__ Xb,
                            const float* __restrict__ c1,
                            const float* __restrict__ c2,
                            unsigned short* __restrict__ W,
                            int nconv) {
  const int bid = blockIdx.x;
  if (bid < nconv) {
    const size_t i = (size_t)bid * 256 + threadIdx.x;   // us8 index
    f32x4 a = ((const f32x4*)X)[i * 2];
    f32x4 b = ((const f32x4*)X)[i * 2 + 1];
    us8 h;
    h[0] = f2bf(a[0]); h[1] = f2bf(a[1]); h[2] = f2bf(a[2]); h[3] = f2bf(a[3]);
    h[4] = f2bf(b[0]); h[5] = f2bf(b[1]); h[6] = f2bf(b[2]); h[7] = f2bf(b[3]);
    ((us8*)Xb)[i] = h;
  } else {
    int idx = (bid - nconv) * 256 + threadIdx.x;   // n*2048 + k
    int k = idx & (K_TOT - 1);
    int n = idx >> 11;
    int i = n >> 9, ob = n & 511;
    int m1 = ob >> 4, m2 = ob & 15;
    int j = k >> 9, ib = k & 511;
    int n1 = ib >> 4, n2 = ib & 15;
    const float* a = c1 + ((((i * 4 + j) * 32 + m1) * 32 + n1) * 16);
    const float* b = c2 + ((i * 4 + j) * 4096 + m2 * 16 + n2);
    float s = 0.f;
#pragma unroll
    for (int r = 0; r < 16; ++r) s += a[r] * b[r * 256];
    W[idx] = f2bf(s);
  }
}

// ---------------------------------------------------------------------------
// Kernel 2: 8-phase 256x256 bf16 GEMM, BK=64, 512 thr (8 waves 2Mx4N).
// LDS 160 KiB: alds[3][2][128x64] (A, 96 KB, period-3) +
//              blds[2][2][128x64] (B, 64 KB, period-2).
// XOR swizzle both-sides. vmcnt: single WAIT(4) per tile at q1.
// ---------------------------------------------------------------------------
__global__ __launch_bounds__(512, 2) void gemm8p_kernel(
    const unsigned short* __restrict__ Xb, const unsigned short* __restrict__ W,
    const float* __restrict__ bias, float* __restrict__ Y) {
  __shared__ __align__(16) unsigned short alds[3][2][128 * 64];  // 96 KB
  __shared__ __align__(16) unsigned short blds[2][2][128 * 64];  // 64 KB

  const int tid = threadIdx.x;
  const int lane = tid & 63;
  const int wid = tid >> 6;
  const int wm = wid >> 2, wn = wid & 3;     // 2 x 4 wave grid

  const int bid = blockIdx.x;
  const int xcd = bid & 7, loc = bid >> 3;
  const int mblk = xcd * 8 + (loc >> 3);     // 0..63
  const int nblk = loc & 7;                  // 0..7
  const int m0 = mblk * 256, n0 = nblk * 256;

  const int fr = lane & 15, g = lane >> 4;
  const int swz = fr & 7;
  const int blkB0 = ((0 + g) ^ swz) * 16;    // ksub=0 byte offset of 16B block
  const int blkB1 = ((4 + g) ^ swz) * 16;    // ksub=1
  const int arow = fr * 128;
  const int brow = ((wn & 1) * 64 + fr) * 128;

  const int sr = tid >> 3;
  const int sc = ((tid & 7) ^ (sr & 7)) * 8;

  auto stageA = [&](int half, int abuf, int kt) {
    const unsigned short* base = Xb + (size_t)(m0 + half * 128) * K_TOT + kt * 64 + sc;
#pragma unroll
    for (int i = 0; i < 2; ++i)
      gld_lds16(base + (size_t)(i * 64 + sr) * K_TOT,
                &alds[abuf][half][i * 4096 + wid * 512]);
  };
  auto stageB = [&](int half, int bbuf, int kt) {
    const unsigned short* base = W + (size_t)(n0 + half * 128) * K_TOT + kt * 64 + sc;
#pragma unroll
    for (int i = 0; i < 2; ++i)
      gld_lds16(base + (size_t)(i * 64 + sr) * K_TOT,
                &blds[bbuf][half][i * 4096 + wid * 512]);
  };
  auto ldA = [&](int abuf, int m, int ks) -> bf16x8 {
    const char* p = (const char*)&alds[abuf][wm][0] + arow + m * 2048 + (ks ? blkB1 : blkB0);
    return *(const bf16x8*)p;
  };
  auto ldB = [&](int bbuf, int n, int ks) -> bf16x8 {
    const char* p = (const char*)&blds[bbuf][wn >> 1][0] + brow + n * 2048 + (ks ? blkB1 : blkB0);
    return *(const bf16x8*)p;
  };

  f32x4 acc[8][4];
#pragma unroll
  for (int m = 0; m < 8; ++m)
#pragma unroll
    for (int n = 0; n < 4; ++n) acc[m][n] = {0.f, 0.f, 0.f, 0.f};

  const int NT = K_TOT / 64;  // 32 K-tiles (even)

  // prologue: A(0)->alds0, B(0)->blds0, B(1)->blds1, A(1)->alds1
  stageA(0, 0, 0); stageA(1, 0, 0);       // 4 loads
  stageB(0, 0, 0); stageB(1, 0, 0);       // 4
  stageB(0, 1, 1); stageB(1, 1, 1);       // 4  (B(1), in flight)
  stageA(0, 1, 1); stageA(1, 1, 1);       // 4  (A(1), in flight)
  WAIT_VM(8);                             // A(0),B(0) landed
  BARRIER();                              // publish tile0

  bf16x8 bqX[4][2], bqY[4][2];
  bf16x8 fa0, fa1, fa2, fa3;              // current phase's A frags
#pragma unroll
  for (int n = 0; n < 4; ++n) {
    bqX[n][0] = ldB(0, n, 0);
    bqX[n][1] = ldB(0, n, 1);
  }
  fa0 = ldA(0, 0, 0); fa1 = ldA(0, 0, 1);
  fa2 = ldA(0, 1, 0); fa3 = ldA(0, 1, 1);

  // body: tile t, B-buf c (=t&1), A-bufs aCur/aNxt/aStg (runtime scalars).
  // q1 WAIT_VM(4): drains A(t+1)+B(t+1) (12 outstanding -> 4 = A(t+2));
  // its pre-MFMA barrier is the publication point for all tail reads of
  // A(t+1)/B(t+1). q3: no wait (steady state).
  auto body = [&](int t, int c, bf16x8 (&bqc)[4][2], bf16x8 (&bqn)[4][2],
                  int aCur, int aNxt, int aStg) {
#pragma unroll
    for (int q = 0; q < 4; ++q) {
      // --- staging + counted vmcnt ---
      if (q == 0 && t + 2 < NT) stageA(0, aStg, t + 2);
      if (q == 1) {
        if (t + 2 < NT) { stageA(1, aStg, t + 2); WAIT_VM(4); }
        else            { WAIT_VM(0); }   // tail tiles: drain everything
      }
      if (q == 2 && t + 2 < NT) stageB(0, c, t + 2);
      if (q == 3 && t + 2 < NT) stageB(1, c, t + 2);
      BARRIER();
      WAIT_LGKM0();   // drains reads issued in PREVIOUS phase's tail (cheap)
      __builtin_amdgcn_s_setprio(1);
      // ksub-outer: 8 independent accs per ksub -> no dependent MFMA pairs
#pragma unroll
      for (int n = 0; n < 4; ++n) {
        acc[2 * q][n]     = __builtin_amdgcn_mfma_f32_16x16x32_bf16(bqc[n][0], fa0, acc[2 * q][n],     0, 0, 0);
        acc[2 * q + 1][n] = __builtin_amdgcn_mfma_f32_16x16x32_bf16(bqc[n][0], fa2, acc[2 * q + 1][n], 0, 0, 0);
      }
#pragma unroll
      for (int n = 0; n < 4; ++n) {
        acc[2 * q][n]     = __builtin_amdgcn_mfma_f32_16x16x32_bf16(bqc[n][1], fa1, acc[2 * q][n],     0, 0, 0);
        acc[2 * q + 1][n] = __builtin_amdgcn_mfma_f32_16x16x32_bf16(bqc[n][1], fa3, acc[2 * q + 1][n], 0, 0, 0);
      }
      __builtin_amdgcn_s_setprio(0);
      // --- tail reads for the NEXT phase (publication-safe) ---
      if (q < 3) {
        fa0 = ldA(aCur, 2 * (q + 1), 0); fa1 = ldA(aCur, 2 * (q + 1), 1);
        fa2 = ldA(aCur, 2 * (q + 1) + 1, 0); fa3 = ldA(aCur, 2 * (q + 1) + 1, 1);
      } else if (t + 1 < NT) {
        // A(t+1): drained at this tile's q1, published at q1's barrier
        fa0 = ldA(aNxt, 0, 0); fa1 = ldA(aNxt, 0, 1);
        fa2 = ldA(aNxt, 1, 0); fa3 = ldA(aNxt, 1, 1);
      }
      if (q == 2 && t + 1 < NT) {   // B(t+1): drained q1, published q1 barrier
        bqn[0][0] = ldB(c ^ 1, 0, 0); bqn[0][1] = ldB(c ^ 1, 0, 1);
        bqn[1][0] = ldB(c ^ 1, 1, 0); bqn[1][1] = ldB(c ^ 1, 1, 1);
      }
      if (q == 3 && t + 1 < NT) {
        bqn[2][0] = ldB(c ^ 1, 2, 0); bqn[2][1] = ldB(c ^ 1, 2, 1);
        bqn[3][0] = ldB(c ^ 1, 3, 0); bqn[3][1] = ldB(c ^ 1, 3, 1);
      }
      BARRIER();
    }
  };

  int a0 = 0, a1 = 1, a2 = 2;   // A-buf rotation (period 3, runtime scalars)
  for (int tt = 0; tt < NT; tt += 2) {
    body(tt,     0, bqX, bqY, a0, a1, a2);   // stages A(tt+2) -> a2
    body(tt + 1, 1, bqY, bqX, a1, a2, a0);   // stages A(tt+3) -> a0
    const int tmp = a0; a0 = a2; a2 = a1; a1 = tmp;  // rotate by 2 tiles
  }

  // epilogue (swapped-D layout, verified rounds 5/6/11/12): M-sub=fr, N-sub=g*4+j.
  f32x4 biasv[4];
#pragma unroll
  for (int n = 0; n < 4; ++n)
    biasv[n] = *(const f32x4*)&bias[n0 + wn * 64 + n * 16 + g * 4];
#pragma unroll
  for (int m = 0; m < 8; ++m) {
    float* rowp = Y + (size_t)(m0 + wm * 128 + m * 16 + fr) * N_TOT;
#pragma unroll
    for (int n = 0; n < 4; ++n) {
      f32x4 v = acc[m][n] + biasv[n];
      *(f32x4*)&rowp[n0 + wn * 64 + n * 16 + g * 4] = v;
    }
  }
}

// ---------------------------------------------------------------------------
// Fallback GEMM (verified round 1): 128^2 tile, in-kernel fp32->bf16 A staging.
// ---------------------------------------------------------------------------
__global__ __launch_bounds__(256, 2) void gemm_fb_kernel(
    const float* __restrict__ X, const unsigned short* __restrict__ W,
    const float* __restrict__ bias, float* __restrict__ Y) {
  __shared__ __align__(16) unsigned short Alds[2][128 * 32];
  __shared__ __align__(16) unsigned short Blds[2][128 * 32];
  const int tid = threadIdx.x;
  const int lane = tid & 63;
  const int wid = tid >> 6;
  const int wm = wid >> 1, wn = wid & 1;
  int bid = blockIdx.x;
  int wgid = (bid & 7) * (2048 / 8) + (bid >> 3);
  const int m0 = (wgid >> 4) * 128, n0 = (wgid & 15) * 128;
  const int ar = tid >> 3, ac = (tid & 7) * 4;
  const int br = (tid >> 2), bc = (tid & 3) * 8;
  f32x4 acc[4][4];
#pragma unroll
  for (int m = 0; m < 4; ++m)
#pragma unroll
    for (int n = 0; n < 4; ++n) acc[m][n] = {0.f, 0.f, 0.f, 0.f};
  f32x4 apre[4];
  auto stA_l = [&](int k0) {
#pragma unroll
    for (int p = 0; p < 4; ++p)
      apre[p] = *(const f32x4*)&X[(size_t)(m0 + p * 32 + ar) * K_TOT + k0 + ac];
  };
  auto stA_w = [&](int buf) {
#pragma unroll
    for (int p = 0; p < 4; ++p) {
      us4 h;
      h[0] = f2bf(apre[p][0]); h[1] = f2bf(apre[p][1]);
      h[2] = f2bf(apre[p][2]); h[3] = f2bf(apre[p][3]);
      *(us4*)&Alds[buf][(p * 32 + ar) * 32 + ac] = h;
    }
  };
  auto stB = [&](int k0, int buf) {
#pragma unroll
    for (int i = 0; i < 2; ++i)
      gld_lds16(&W[(size_t)(n0 + i * 64 + br) * K_TOT + k0 + bc],
                &Blds[buf][i * 2048 + wid * 512]);
  };
  auto comp = [&](int buf) {
    const unsigned short* Ab = &Alds[buf][(wm * 64 + (lane & 15)) * 32 + (lane >> 4) * 8];
    const unsigned short* Bb = &Blds[buf][(wn * 64 + (lane & 15)) * 32 + (lane >> 4) * 8];
    bf16x8 af[4], bfv[4];
#pragma unroll
    for (int m = 0; m < 4; ++m) af[m] = *(const bf16x8*)(Ab + m * 16 * 32);
#pragma unroll
    for (int n = 0; n < 4; ++n) bfv[n] = *(const bf16x8*)(Bb + n * 16 * 32);
#pragma unroll
    for (int m = 0; m < 4; ++m)
#pragma unroll
      for (int n = 0; n < 4; ++n)
        acc[m][n] = __builtin_amdgcn_mfma_f32_16x16x32_bf16(af[m], bfv[n], acc[m][n], 0, 0, 0);
  };
  stA_l(0); stB(0, 0); stA_w(0);
  __syncthreads();
  for (int kt = 0; kt < 64; ++kt) {
    const int cur = kt & 1, nxt = cur ^ 1;
    if (kt + 1 < 64) { stA_l((kt + 1) * 32); stB((kt + 1) * 32, nxt); }
    comp(cur);
    if (kt + 1 < 64) stA_w(nxt);
    __syncthreads();
  }
  const int col = lane & 15, rb = (lane >> 4) * 4;
#pragma unroll
  for (int n = 0; n < 4; ++n) {
    const int gc = n0 + wn * 64 + n * 16 + col;
    const float bv = bias[gc];
#pragma unroll
    for (int m = 0; m < 4; ++m)
#pragma unroll
      for (int j = 0; j < 4; ++j)
        Y[(size_t)(m0 + wm * 64 + m * 16 + rb + j) * N_TOT + gc] = acc[m][n][j] + bv;
  }
}

extern "C" void kernel_launch(void* const* d_in, const int* in_sizes, int n_in,
                              void* d_out, int out_size, void* d_ws, size_t ws_size,
                              hipStream_t stream) {
  const float* x    = (const float*)d_in[0];
  const float* c1   = (const float*)d_in[1];
  const float* c2   = (const float*)d_in[2];
  const float* bias = (const float*)d_in[3];
  float* y          = (float*)d_out;
  unsigned short* W = (unsigned short*)d_ws;                        // 8 MB
  unsigned short* Xb = (unsigned short*)((char*)d_ws + (8u << 20)); // 64 MB

  const size_t need = (size_t)(8u << 20) + (size_t)M_TOT * K_TOT * 2;
  if (ws_size >= need) {
    prep_kernel<<<16384 + 16384, 256, 0, stream>>>(x, Xb, c1, c2, W, 16384);
    gemm8p_kernel<<<(M_TOT / 256) * (N_TOT / 256), 512, 0, stream>>>(Xb, W, bias, y);
  } else {
    prep_kernel<<<16384, 256, 0, stream>>>(x, nullptr, c1, c2, W, 0);  // W only
    gemm_fb_kernel<<<(M_TOT / 128) * (N_TOT / 128), 256, 0, stream>>>(x, W, bias, y);
  }
}

// Round 14
// 178.070 us; speedup vs baseline: 1.1143x; 1.1143x over previous
//
#include <hip/hip_runtime.h>
#include <stdint.h>

// y[b,s,m] = sum_n x[b,s,n] * W[m,n] + bias[m], W from TT cores (bf16, built once).
// Pipeline: prep (build_w + convert_x fused, one dispatch) -> 8-phase 256^2 GEMM.
// GEMM: A = bf16 X (pre-converted), B = bf16 W, both via global_load_lds.
// VERIFIED-BEST (round 12, passed twice incl. timed-replay revalidation):
// - both-sides XOR swizzle (inverse-swizzled global source + swizzled ds_read)
// - counted vmcnt chain (q1 drains own B(t+1) -> publication; q3 drains A(t+1))
// - B frags register-pipelined across tiles (static ping/pong, reads at q2/q3
//   tails AFTER the publication barrier - race-proof drain->barrier->read)
// - frag ds_reads in post-MFMA tail of previous phase (lgkmcnt(0) cheap)
// - ksub-outer MFMA order (8 independent accs, no dependent pairs)
// - MFMA operands swapped (W-frag first) -> D transposed -> f32x4 stores.
// Falsified alternatives: 32x32 MFMA (bank conflicts, r8), A-reg fusion
// (VGPR spill, r4), 3-buffer A (runtime LDS indexing, r13), dropped lgkm /
// q1-reads (races, r9/r10).

typedef __attribute__((ext_vector_type(8))) __bf16 bf16x8;
typedef __attribute__((ext_vector_type(4))) float f32x4;
typedef __attribute__((ext_vector_type(4))) unsigned short us4;
typedef __attribute__((ext_vector_type(8))) unsigned short us8;

#define M_TOT 16384
#define N_TOT 2048
#define K_TOT 2048

__device__ __forceinline__ unsigned short f2bf(float f) {
  union { float f; unsigned u; } v; v.f = f;
  unsigned u = v.u;
  u += 0x7FFFu + ((u >> 16) & 1u);   // RNE
  return (unsigned short)(u >> 16);
}

__device__ __forceinline__ void gld_lds16(const void* g, void* l) {
  __builtin_amdgcn_global_load_lds(
      (const __attribute__((address_space(1))) unsigned int*)g,
      (__attribute__((address_space(3))) unsigned int*)l, 16, 0, 0);
}

#define BARRIER() __builtin_amdgcn_s_barrier()
#define WAIT_LGKM0() asm volatile("s_waitcnt lgkmcnt(0)" ::: "memory")
#define WAIT_VM(N) asm volatile("s_waitcnt vmcnt(" #N ")" ::: "memory")

// ---------------------------------------------------------------------------
// Kernel 1: fused prep. Blocks [0,nconv): X fp32->bf16 (1 us8/thread);
// blocks [nconv, nconv+16384): build W bf16 from TT cores.
// ---------------------------------------------------------------------------
__global__ void prep_kernel(const float* __restrict__ X,
                            unsigned short* __restrict__ Xb,
                            const float* __restrict__ c1,
                            const float* __restrict__ c2,
                            unsigned short* __restrict__ W,
                            int nconv) {
  const int bid = blockIdx.x;
  if (bid < nconv) {
    const size_t i = (size_t)bid * 256 + threadIdx.x;   // us8 index
    f32x4 a = ((const f32x4*)X)[i * 2];
    f32x4 b = ((const f32x4*)X)[i * 2 + 1];
    us8 h;
    h[0] = f2bf(a[0]); h[1] = f2bf(a[1]); h[2] = f2bf(a[2]); h[3] = f2bf(a[3]);
    h[4] = f2bf(b[0]); h[5] = f2bf(b[1]); h[6] = f2bf(b[2]); h[7] = f2bf(b[3]);
    ((us8*)Xb)[i] = h;
  } else {
    int idx = (bid - nconv) * 256 + threadIdx.x;   // n*2048 + k
    int k = idx & (K_TOT - 1);
    int n = idx >> 11;
    int i = n >> 9, ob = n & 511;
    int m1 = ob >> 4, m2 = ob & 15;
    int j = k >> 9, ib = k & 511;
    int n1 = ib >> 4, n2 = ib & 15;
    const float* a = c1 + ((((i * 4 + j) * 32 + m1) * 32 + n1) * 16);
    const float* b = c2 + ((i * 4 + j) * 4096 + m2 * 16 + n2);
    float s = 0.f;
#pragma unroll
    for (int r = 0; r < 16; ++r) s += a[r] * b[r * 256];
    W[idx] = f2bf(s);
  }
}

// ---------------------------------------------------------------------------
// Kernel 2: 8-phase 256x256 bf16 GEMM, BK=64, 512 thr (8 waves 2Mx4N).
// LDS 128 KiB: [buf2][sect4][128x64 bf16]; sect 0/1 = A halves, 2/3 = B halves.
// XOR swizzle both-sides. vmcnt chain: q1 WAIT(4) drains own B(t+1) (publication
// point for q2/q3-tail reads); q3 WAIT(4) drains A(t+1) (publication point for
// q3-tail next-tile A reads). Never 0 mid-loop.
// ---------------------------------------------------------------------------
__global__ __launch_bounds__(512, 2) void gemm8p_kernel(
    const unsigned short* __restrict__ Xb, const unsigned short* __restrict__ W,
    const float* __restrict__ bias, float* __restrict__ Y) {
  __shared__ __align__(16) unsigned short lds[2][4][128 * 64];

  const int tid = threadIdx.x;
  const int lane = tid & 63;
  const int wid = tid >> 6;
  const int wm = wid >> 2, wn = wid & 3;     // 2 x 4 wave grid

  const int bid = blockIdx.x;
  const int xcd = bid & 7, loc = bid >> 3;
  const int mblk = xcd * 8 + (loc >> 3);     // 0..63
  const int nblk = loc & 7;                  // 0..7
  const int m0 = mblk * 256, n0 = nblk * 256;

  const int fr = lane & 15, g = lane >> 4;
  const int swz = fr & 7;
  const int blkB0 = ((0 + g) ^ swz) * 16;    // ksub=0 byte offset of 16B block
  const int blkB1 = ((4 + g) ^ swz) * 16;    // ksub=1
  const int arow = fr * 128;
  const int brow = ((wn & 1) * 64 + fr) * 128;

  const int sr = tid >> 3;
  const int sc = ((tid & 7) ^ (sr & 7)) * 8;

  auto stageA = [&](int half, int buf, int kt) {
    const unsigned short* base = Xb + (size_t)(m0 + half * 128) * K_TOT + kt * 64 + sc;
#pragma unroll
    for (int i = 0; i < 2; ++i)
      gld_lds16(base + (size_t)(i * 64 + sr) * K_TOT,
                &lds[buf][half][i * 4096 + wid * 512]);
  };
  auto stageB = [&](int half, int buf, int kt) {
    const unsigned short* base = W + (size_t)(n0 + half * 128) * K_TOT + kt * 64 + sc;
#pragma unroll
    for (int i = 0; i < 2; ++i)
      gld_lds16(base + (size_t)(i * 64 + sr) * K_TOT,
                &lds[buf][2 + half][i * 4096 + wid * 512]);
  };
  auto ldA = [&](int c, int m, int ks) -> bf16x8 {
    const char* p = (const char*)&lds[c][wm][0] + arow + m * 2048 + (ks ? blkB1 : blkB0);
    return *(const bf16x8*)p;
  };
  auto ldB = [&](int c, int n, int ks) -> bf16x8 {
    const char* p = (const char*)&lds[c][2 + (wn >> 1)][0] + brow + n * 2048 + (ks ? blkB1 : blkB0);
    return *(const bf16x8*)p;
  };

  f32x4 acc[8][4];
#pragma unroll
  for (int m = 0; m < 8; ++m)
#pragma unroll
    for (int n = 0; n < 4; ++n) acc[m][n] = {0.f, 0.f, 0.f, 0.f};

  const int NT = K_TOT / 64;  // 32 K-tiles (even)

  // prologue: tile0 (A+B) -> buf0, B of tile1 -> buf1
  stageA(0, 0, 0); stageA(1, 0, 0);       // 4 loads
  stageB(0, 0, 0); stageB(1, 0, 0);       // 4
  stageB(0, 1, 1); stageB(1, 1, 1);       // 4 (tile1 B)
  WAIT_VM(4);                             // A(0),B(0) landed; B(1) in flight
  BARRIER();                              // publish tile0 to all waves

  bf16x8 bqX[4][2], bqY[4][2];
  bf16x8 fa0, fa1, fa2, fa3;              // current phase's A frags (SSA-renamed)
  // tile0 B frags + tile0 q0 A frags (post-barrier => safe; drained by first lgkmcnt(0))
#pragma unroll
  for (int n = 0; n < 4; ++n) {
    bqX[n][0] = ldB(0, n, 0);
    bqX[n][1] = ldB(0, n, 1);
  }
  fa0 = ldA(0, 0, 0); fa1 = ldA(0, 0, 1);
  fa2 = ldA(0, 1, 0); fa3 = ldA(0, 1, 1);

  auto body = [&](int t, int c, bf16x8 (&bqc)[4][2], bf16x8 (&bqn)[4][2]) {
#pragma unroll
    for (int q = 0; q < 4; ++q) {
      // --- staging + counted vmcnt (identical to verified round 11) ---
      if (q == 0 && t + 1 < NT) stageA(0, c ^ 1, t + 1);
      if (q == 1 && t + 1 < NT) {
        stageA(1, c ^ 1, t + 1);
        WAIT_VM(4);    // drain own B(t+1); q1's pre-MFMA barrier publishes it
      }
      if (q == 2 && t + 2 < NT) stageB(0, c, t + 2);
      if (q == 3) {
        if (t + 2 < NT) { stageB(1, c, t + 2); WAIT_VM(4); }  // A(t+1) drained
        else            { WAIT_VM(0); }                        // tail drain
      }
      BARRIER();
      WAIT_LGKM0();   // drains reads issued in PREVIOUS phase's tail (cheap now)
      __builtin_amdgcn_s_setprio(1);
      // ksub-outer: 8 independent accs per ksub -> no dependent MFMA pairs
#pragma unroll
      for (int n = 0; n < 4; ++n) {
        acc[2 * q][n]     = __builtin_amdgcn_mfma_f32_16x16x32_bf16(bqc[n][0], fa0, acc[2 * q][n],     0, 0, 0);
        acc[2 * q + 1][n] = __builtin_amdgcn_mfma_f32_16x16x32_bf16(bqc[n][0], fa2, acc[2 * q + 1][n], 0, 0, 0);
      }
#pragma unroll
      for (int n = 0; n < 4; ++n) {
        acc[2 * q][n]     = __builtin_amdgcn_mfma_f32_16x16x32_bf16(bqc[n][1], fa1, acc[2 * q][n],     0, 0, 0);
        acc[2 * q + 1][n] = __builtin_amdgcn_mfma_f32_16x16x32_bf16(bqc[n][1], fa3, acc[2 * q + 1][n], 0, 0, 0);
      }
      __builtin_amdgcn_s_setprio(0);
      // --- tail reads for the NEXT phase (publication-safe, see header) ---
      if (q < 3) {
        fa0 = ldA(c, 2 * (q + 1), 0); fa1 = ldA(c, 2 * (q + 1), 1);
        fa2 = ldA(c, 2 * (q + 1) + 1, 0); fa3 = ldA(c, 2 * (q + 1) + 1, 1);
      } else if (t + 1 < NT) {
        // next tile's q0 frags: A(t+1) published at q3's open barrier
        fa0 = ldA(c ^ 1, 0, 0); fa1 = ldA(c ^ 1, 0, 1);
        fa2 = ldA(c ^ 1, 1, 0); fa3 = ldA(c ^ 1, 1, 1);
      }
      if (q == 2 && t + 1 < NT) {   // B(t+1) published at q1's open barrier
        bqn[0][0] = ldB(c ^ 1, 0, 0); bqn[0][1] = ldB(c ^ 1, 0, 1);
        bqn[1][0] = ldB(c ^ 1, 1, 0); bqn[1][1] = ldB(c ^ 1, 1, 1);
      }
      if (q == 3 && t + 1 < NT) {
        bqn[2][0] = ldB(c ^ 1, 2, 0); bqn[2][1] = ldB(c ^ 1, 2, 1);
        bqn[3][0] = ldB(c ^ 1, 3, 0); bqn[3][1] = ldB(c ^ 1, 3, 1);
      }
      BARRIER();
    }
  };

  for (int tt = 0; tt < NT; tt += 2) {
    body(tt,     0, bqX, bqY);   // uses bqX, prefetches tile tt+1 B -> bqY
    body(tt + 1, 1, bqY, bqX);   // uses bqY, prefetches tile tt+2 B -> bqX
  }

  // epilogue (swapped-D layout, verified rounds 5/6/11/12): M-sub=fr, N-sub=g*4+j.
  f32x4 biasv[4];
#pragma unroll
  for (int n = 0; n < 4; ++n)
    biasv[n] = *(const f32x4*)&bias[n0 + wn * 64 + n * 16 + g * 4];
#pragma unroll
  for (int m = 0; m < 8; ++m) {
    float* rowp = Y + (size_t)(m0 + wm * 128 + m * 16 + fr) * N_TOT;
#pragma unroll
    for (int n = 0; n < 4; ++n) {
      f32x4 v = acc[m][n] + biasv[n];
      *(f32x4*)&rowp[n0 + wn * 64 + n * 16 + g * 4] = v;
    }
  }
}

// ---------------------------------------------------------------------------
// Fallback GEMM (verified round 1): 128^2 tile, in-kernel fp32->bf16 A staging.
// ---------------------------------------------------------------------------
__global__ __launch_bounds__(256, 2) void gemm_fb_kernel(
    const float* __restrict__ X, const unsigned short* __restrict__ W,
    const float* __restrict__ bias, float* __restrict__ Y) {
  __shared__ __align__(16) unsigned short Alds[2][128 * 32];
  __shared__ __align__(16) unsigned short Blds[2][128 * 32];
  const int tid = threadIdx.x;
  const int lane = tid & 63;
  const int wid = tid >> 6;
  const int wm = wid >> 1, wn = wid & 1;
  int bid = blockIdx.x;
  int wgid = (bid & 7) * (2048 / 8) + (bid >> 3);
  const int m0 = (wgid >> 4) * 128, n0 = (wgid & 15) * 128;
  const int ar = tid >> 3, ac = (tid & 7) * 4;
  const int br = (tid >> 2), bc = (tid & 3) * 8;
  f32x4 acc[4][4];
#pragma unroll
  for (int m = 0; m < 4; ++m)
#pragma unroll
    for (int n = 0; n < 4; ++n) acc[m][n] = {0.f, 0.f, 0.f, 0.f};
  f32x4 apre[4];
  auto stA_l = [&](int k0) {
#pragma unroll
    for (int p = 0; p < 4; ++p)
      apre[p] = *(const f32x4*)&X[(size_t)(m0 + p * 32 + ar) * K_TOT + k0 + ac];
  };
  auto stA_w = [&](int buf) {
#pragma unroll
    for (int p = 0; p < 4; ++p) {
      us4 h;
      h[0] = f2bf(apre[p][0]); h[1] = f2bf(apre[p][1]);
      h[2] = f2bf(apre[p][2]); h[3] = f2bf(apre[p][3]);
      *(us4*)&Alds[buf][(p * 32 + ar) * 32 + ac] = h;
    }
  };
  auto stB = [&](int k0, int buf) {
#pragma unroll
    for (int i = 0; i < 2; ++i)
      gld_lds16(&W[(size_t)(n0 + i * 64 + br) * K_TOT + k0 + bc],
                &Blds[buf][i * 2048 + wid * 512]);
  };
  auto comp = [&](int buf) {
    const unsigned short* Ab = &Alds[buf][(wm * 64 + (lane & 15)) * 32 + (lane >> 4) * 8];
    const unsigned short* Bb = &Blds[buf][(wn * 64 + (lane & 15)) * 32 + (lane >> 4) * 8];
    bf16x8 af[4], bfv[4];
#pragma unroll
    for (int m = 0; m < 4; ++m) af[m] = *(const bf16x8*)(Ab + m * 16 * 32);
#pragma unroll
    for (int n = 0; n < 4; ++n) bfv[n] = *(const bf16x8*)(Bb + n * 16 * 32);
#pragma unroll
    for (int m = 0; m < 4; ++m)
#pragma unroll
      for (int n = 0; n < 4; ++n)
        acc[m][n] = __builtin_amdgcn_mfma_f32_16x16x32_bf16(af[m], bfv[n], acc[m][n], 0, 0, 0);
  };
  stA_l(0); stB(0, 0); stA_w(0);
  __syncthreads();
  for (int kt = 0; kt < 64; ++kt) {
    const int cur = kt & 1, nxt = cur ^ 1;
    if (kt + 1 < 64) { stA_l((kt + 1) * 32); stB((kt + 1) * 32, nxt); }
    comp(cur);
    if (kt + 1 < 64) stA_w(nxt);
    __syncthreads();
  }
  const int col = lane & 15, rb = (lane >> 4) * 4;
#pragma unroll
  for (int n = 0; n < 4; ++n) {
    const int gc = n0 + wn * 64 + n * 16 + col;
    const float bv = bias[gc];
#pragma unroll
    for (int m = 0; m < 4; ++m)
#pragma unroll
      for (int j = 0; j < 4; ++j)
        Y[(size_t)(m0 + wm * 64 + m * 16 + rb + j) * N_TOT + gc] = acc[m][n][j] + bv;
  }
}

extern "C" void kernel_launch(void* const* d_in, const int* in_sizes, int n_in,
                              void* d_out, int out_size, void* d_ws, size_t ws_size,
                              hipStream_t stream) {
  const float* x    = (const float*)d_in[0];
  const float* c1   = (const float*)d_in[1];
  const float* c2   = (const float*)d_in[2];
  const float* bias = (const float*)d_in[3];
  float* y          = (float*)d_out;
  unsigned short* W = (unsigned short*)d_ws;                        // 8 MB
  unsigned short* Xb = (unsigned short*)((char*)d_ws + (8u << 20)); // 64 MB

  const size_t need = (size_t)(8u << 20) + (size_t)M_TOT * K_TOT * 2;
  if (ws_size >= need) {
    prep_kernel<<<16384 + 16384, 256, 0, stream>>>(x, Xb, c1, c2, W, 16384);
    gemm8p_kernel<<<(M_TOT / 256) * (N_TOT / 256), 512, 0, stream>>>(Xb, W, bias, y);
  } else {
    prep_kernel<<<16384, 256, 0, stream>>>(x, nullptr, c1, c2, W, 0);  // W only
    gemm_fb_kernel<<<(M_TOT / 128) * (N_TOT / 128), 256, 0, stream>>>(x, W, bias, y);
  }
}